// Round 17
// baseline (67.315 us; speedup 1.0000x reference)
//
#include <hip/hip_runtime.h>
#include <hip/hip_fp16.h>

// PhotometricLoss: total = 0.8*L1 + 0.2*DSSIM; fused separable 11x11 Gaussian
// SSIM, SAME zero padding. Inputs BHWC fp32 (B=4,H=1080,W=1920,C=3).
// R17 (= R16 + latency pipelining): staging runs a 2-deep rotation (issue
// item i+1's global loads before processing item i) and the conv phase
// prefetches channel ch+1's LDS fragments before computing channel ch.
// VGPR 36 -> ~68 (budget 73 at 7 waves/EU). Everything else as R16.

typedef __fp16 hf4 __attribute__((ext_vector_type(4)));
typedef float f32x4 __attribute__((ext_vector_type(4)));

#define TW 32
#define TH 32
#define IH 42         // staged real rows
#define NPAIR 21      // data col-pairs per row
#define SPAIR 22      // row stride in uint2 (176 B; 12-bank rotation, ~2-way)
#define CHS (IH * SPAIR)   // uint2 per channel plane (924)
#define NSLOT 512
#define HH 1080
#define WW 1920
#define GX 60
#define GY 34

// Gaussian(sigma=1.5, 11 taps), normalized; matches fp32 reference within ~2e-7
static constexpr float G[11] = {
    0.00102838f, 0.00759876f, 0.03600077f, 0.10936069f, 0.21300554f,
    0.26601174f, 0.21300554f, 0.10936069f, 0.03600077f, 0.00759876f,
    0.00102838f};

// ---- constexpr f32 -> f16 bits (RNE); G values are all f16-normal
constexpr unsigned short f2h_cx(float f) {
    unsigned u = __builtin_bit_cast(unsigned, f);
    if ((u & 0x7fffffffu) == 0) return 0;
    int e = (int)((u >> 23) & 0xff) - 127 + 15;
    unsigned man = u & 0x7fffffu;
    unsigned m = man >> 13;
    unsigned rest = man & 0x1fffu;
    if (rest > 0x1000u || (rest == 0x1000u && (m & 1u))) {
        if (++m == 0x400u) { m = 0; ++e; }
    }
    return (unsigned short)((e << 10) | m);
}
constexpr float Gf(int d) { return (d >= 0 && d <= 10) ? G[d] : 0.0f; }
constexpr unsigned wpk(int d) {
    return (unsigned)f2h_cx(Gf(d)) | ((unsigned)f2h_cx(Gf(d + 1)) << 16);
}
// Band fragment tables (the only two nonzero tile-deltas):
// idx 0: halves g[lk - lr + i]; idx 1: g[16 + lk - lr + i].
struct WTbl {
    unsigned long long v[2][64];
    constexpr WTbl() : v{} {
        for (int dl = 0; dl < 2; ++dl)
            for (int l = 0; l < 64; ++l) {
                int d0 = 16 * dl + ((l >> 4) << 2) - (l & 15);
                v[dl][l] = (unsigned long long)wpk(d0) |
                           ((unsigned long long)wpk(d0 + 2) << 32);
            }
    }
};
__device__ const WTbl WT{};

struct f4u { float x, y, z, w; } __attribute__((packed, aligned(4)));

__device__ __forceinline__ unsigned int pkrtz(float a, float b) {
    return __builtin_bit_cast(unsigned int, __builtin_amdgcn_cvt_pkrtz(a, b));
}
__device__ __forceinline__ hf4 pk4(const f32x4& d) {
    uint2 u = make_uint2(pkrtz(d[0], d[1]), pkrtz(d[2], d[3]));
    return __builtin_bit_cast(hf4, u);
}
__device__ __forceinline__ f32x4 mfma16(hf4 a, hf4 b, f32x4 c) {
#if defined(__HIP_DEVICE_COMPILE__)
    return __builtin_amdgcn_mfma_f32_16x16x16f16(a, b, c, 0, 0, 0);
#else
    (void)a; (void)b;
    return c;   // host pass: never executed, just needs to parse
#endif
}

__global__ __launch_bounds__(256, 7) void photo_main(
    const float* __restrict__ xin, const float* __restrict__ yin,
    double* __restrict__ accum, int B, int nwg)
{
    __shared__ __align__(16) uint2 sXY[3 * CHS + 2];  // 22192 B, channel-outer
    __shared__ float red[8];

    // ---- bijective XCD swizzle (nwg % 8 == 0)
    int orig = blockIdx.x + GX * (blockIdx.y + GY * blockIdx.z);
    int nid = ((nwg & 7) == 0) ? ((orig & 7) * (nwg >> 3) + (orig >> 3)) : orig;
    int tx   = nid % GX;
    int rest = nid / GX;
    int by   = rest % GY;
    int b    = rest / GY;
    const int row0 = by * TH, col0 = tx * TW;
    const int tid  = threadIdx.x;
    const int lane = tid & 63;
    const int wid  = tid >> 6;
    const int imgbase = b * (HH * WW * 3);

    // ---- finite-fill: pair 21 of every (ch, row) + 2 slack words past ch2.
    // Read by the h-pass k2=2 tail with structurally-zero weights; must be
    // finite (not necessarily zero) to avoid NaN*0 in MFMA.
    if (tid < 126) {
        int ch = tid / IH, r = tid - ch * IH;
        sXY[ch * CHS + r * SPAIR + NPAIR] = make_uint2(0u, 0u);
    } else if (tid < 128) {
        sXY[3 * CHS + (tid - 126)] = make_uint2(0u, 0u);
    }

    // ---- Phase 1a: stage all 3 channels as interleaved (x,y) f16 pairs;
    // fold L1 over the central 32x32. Interior path: 2-deep load rotation.
    float l1_sum = 0.f;
    const bool interior = (tx >= 1) && (tx <= 58) && (by >= 1) && (by <= 32);
    if (interior) {
        int i = tid;
        int r = i / NPAIR, pc = i - r * NPAIR;
        {
            int gr = row0 - 5 + r, gc0 = col0 - 5 + 2 * pc;
            int base = imgbase + (gr * WW + gc0) * 3;
            // current item's loads (prologue)
            f4u vx0 = *(const f4u*)&xin[base];
            f4u vx1 = *(const f4u*)&xin[base + 2];
            f4u vy0 = *(const f4u*)&yin[base];
            f4u vy1 = *(const f4u*)&yin[base + 2];
            #pragma unroll 1
            for (;;) {
                int inext = i + 256;
                bool more = inext < IH * NPAIR;
                int rn = 0, pcn = 0;
                f4u nx0, nx1, ny0, ny1;
                if (more) {      // issue NEXT loads before consuming current
                    rn = inext / NPAIR; pcn = inext - rn * NPAIR;
                    int grn = row0 - 5 + rn, gcn = col0 - 5 + 2 * pcn;
                    int bn = imgbase + (grn * WW + gcn) * 3;
                    nx0 = *(const f4u*)&xin[bn];
                    nx1 = *(const f4u*)&xin[bn + 2];
                    ny0 = *(const f4u*)&yin[bn];
                    ny1 = *(const f4u*)&yin[bn + 2];
                }
                float x0[3] = {vx0.x, vx0.y, vx0.z};
                float x1[3] = {vx1.y, vx1.z, vx1.w};
                float y0[3] = {vy0.x, vy0.y, vy0.z};
                float y1[3] = {vy1.y, vy1.z, vy1.w};
                #pragma unroll
                for (int c = 0; c < 3; ++c)
                    sXY[c * CHS + r * SPAIR + pc] =
                        make_uint2(pkrtz(x0[c], x1[c]), pkrtz(y0[c], y1[c]));
                if (r >= 5 && r < 5 + TH) {
                    if (pc >= 3 && pc <= 18)
                        l1_sum += fabsf(x0[0] - y0[0]) + fabsf(x0[1] - y0[1]) +
                                  fabsf(x0[2] - y0[2]);
                    if (pc >= 2 && pc <= 17)
                        l1_sum += fabsf(x1[0] - y1[0]) + fabsf(x1[1] - y1[1]) +
                                  fabsf(x1[2] - y1[2]);
                }
                if (!more) break;
                i = inext; r = rn; pc = pcn;
                vx0 = nx0; vx1 = nx1; vy0 = ny0; vy1 = ny1;
            }
        }
    } else {
        #pragma unroll 1
        for (int i = tid; i < IH * NPAIR; i += 256) {
            int r  = i / NPAIR;
            int pc = i - r * NPAIR;
            int gr  = row0 - 5 + r;
            int gc0 = col0 - 5 + 2 * pc;
            bool rin = (unsigned)gr < (unsigned)HH;
            bool c0  = rin && ((unsigned)gc0       < (unsigned)WW);
            bool c1  = rin && ((unsigned)(gc0 + 1) < (unsigned)WW);
            int base = imgbase + (gr * WW + gc0) * 3;
            float x0[3] = {0.f, 0.f, 0.f}, x1[3] = {0.f, 0.f, 0.f};
            float y0[3] = {0.f, 0.f, 0.f}, y1[3] = {0.f, 0.f, 0.f};
            #pragma unroll
            for (int c = 0; c < 3; ++c) {
                if (c0) { x0[c] = xin[base + c];     y0[c] = yin[base + c]; }
                if (c1) { x1[c] = xin[base + 3 + c]; y1[c] = yin[base + 3 + c]; }
            }
            #pragma unroll
            for (int c = 0; c < 3; ++c)
                sXY[c * CHS + r * SPAIR + pc] =
                    make_uint2(pkrtz(x0[c], x1[c]), pkrtz(y0[c], y1[c]));
            if (r >= 5 && r < 5 + TH) {
                if (c0 && pc >= 3 && pc <= 18)
                    l1_sum += fabsf(x0[0] - y0[0]) + fabsf(x0[1] - y0[1]) +
                              fabsf(x0[2] - y0[2]);
                if (c1 && pc >= 2 && pc <= 17)
                    l1_sum += fabsf(x1[0] - y1[0]) + fabsf(x1[1] - y1[1]) +
                              fabsf(x1[2] - y1[2]);
            }
        }
    }
    __syncthreads();

    // ---- quadrant-per-wave conv: wave wid -> out quadrant (u,n), 16x16,
    // all 4 moment planes; register-chained h->v; SSIM from registers.
    // Channel loop runs a 2-deep LDS-read rotation.
    const int lr = lane & 15;
    const int lk = (lane >> 4) << 2;
    const int u = wid >> 1, n = wid & 1;
    hf4 wfA = __builtin_bit_cast(hf4, WT.v[0][lane]);
    hf4 wfB = __builtin_bit_cast(hf4, WT.v[1][lane]);

    // clamped read rows: rows >= 42 (only t=2, lr >= 10) fold to row 41;
    // the garbage HC rows 42..47 carry structurally-zero v-pass weights.
    int rrow[2];
    #pragma unroll
    for (int dt = 0; dt < 2; ++dt)
        rrow[dt] = min(16 * (u + dt) + lr, IH - 1) * SPAIR;

    const float C1c = 1e-4f, C2c = 9e-4f;
    float ssim_sum = 0.f;
    const bool fullq = (row0 + 16 * u + 15) < HH;   // whole quadrant in-image
    uint4 rd[2][2];
    #pragma unroll
    for (int dt = 0; dt < 2; ++dt)
        #pragma unroll
        for (int dk = 0; dk < 2; ++dk)
            rd[dt][dk] = *(const uint4*)&sXY[rrow[dt] + 8 * (n + dk) + (lk >> 1)];
    #pragma unroll 1
    for (int ch = 0; ch < 3; ++ch) {
        uint4 rn4[2][2];
        if (ch < 2) {       // prefetch next channel's fragments
            const uint2* Sn = sXY + (ch + 1) * CHS;
            #pragma unroll
            for (int dt = 0; dt < 2; ++dt)
                #pragma unroll
                for (int dk = 0; dk < 2; ++dk)
                    rn4[dt][dk] = *(const uint4*)
                        &Sn[rrow[dt] + 8 * (n + dk) + (lk >> 1)];
        }
        // h-pass: HC tiles t=u,u+1 for col-block n, 4 planes
        hf4 bfr[4][2];
        #pragma unroll
        for (int dt = 0; dt < 2; ++dt) {
            f32x4 d[4];
            #pragma unroll
            for (int p = 0; p < 4; ++p) d[p] = (f32x4){0.f, 0.f, 0.f, 0.f};
            #pragma unroll
            for (int dk = 0; dk < 2; ++dk) {
                uint4 v = rd[dt][dk];
                hf4 xv = __builtin_bit_cast(hf4, make_uint2(v.x, v.z));
                hf4 yv = __builtin_bit_cast(hf4, make_uint2(v.y, v.w));
                hf4 zv = xv * xv + yv * yv;
                hf4 wv = xv * yv;
                hf4 wB = dk ? wfB : wfA;
                d[0] = mfma16(xv, wB, d[0]);
                d[1] = mfma16(yv, wB, d[1]);
                d[2] = mfma16(zv, wB, d[2]);
                d[3] = mfma16(wv, wB, d[3]);
            }
            #pragma unroll
            for (int p = 0; p < 4; ++p) bfr[p][dt] = pk4(d[p]);
        }
        // v-pass: OUT quadrant = Wv x HC
        f32x4 vacc[4];
        #pragma unroll
        for (int p = 0; p < 4; ++p) {
            vacc[p] = (f32x4){0.f, 0.f, 0.f, 0.f};
            vacc[p] = mfma16(wfA, bfr[p][0], vacc[p]);
            vacc[p] = mfma16(wfB, bfr[p][1], vacc[p]);
        }
        // SSIM directly from registers
        if (fullq) {
            #pragma unroll
            for (int g2 = 0; g2 < 4; ++g2) {
                float mu1 = vacc[0][g2], mu2 = vacc[1][g2];
                float s2s = vacc[2][g2], s12 = vacc[3][g2];
                float mu1s = mu1 * mu1, mu2s = mu2 * mu2, mu12 = mu1 * mu2;
                float ssum = s2s - mu1s - mu2s;
                float sxy  = s12 - mu12;
                float num = (2.f * mu12 + C1c) * (2.f * sxy + C2c);
                float den = (mu1s + mu2s + C1c) * (ssum + C2c);
                ssim_sum += num * __builtin_amdgcn_rcpf(den);
            }
        } else {
            #pragma unroll
            for (int g2 = 0; g2 < 4; ++g2) {
                int gr = row0 + 16 * u + lk + g2;
                if (gr < HH) {
                    float mu1 = vacc[0][g2], mu2 = vacc[1][g2];
                    float s2s = vacc[2][g2], s12 = vacc[3][g2];
                    float mu1s = mu1 * mu1, mu2s = mu2 * mu2, mu12 = mu1 * mu2;
                    float ssum = s2s - mu1s - mu2s;
                    float sxy  = s12 - mu12;
                    float num = (2.f * mu12 + C1c) * (2.f * sxy + C2c);
                    float den = (mu1s + mu2s + C1c) * (ssum + C2c);
                    ssim_sum += num * __builtin_amdgcn_rcpf(den);
                }
            }
        }
        if (ch < 2) {
            #pragma unroll
            for (int dt = 0; dt < 2; ++dt)
                #pragma unroll
                for (int dk = 0; dk < 2; ++dk)
                    rd[dt][dk] = rn4[dt][dk];
        }
    }

    // ---- Block reduction, then hashed double atomics
    #pragma unroll
    for (int off = 32; off > 0; off >>= 1) {
        ssim_sum += __shfl_down(ssim_sum, off);
        l1_sum   += __shfl_down(l1_sum, off);
    }
    if ((tid & 63) == 0) { red[wid] = ssim_sum; red[4 + wid] = l1_sum; }
    __syncthreads();
    if (tid == 0) {
        float s = red[0] + red[1] + red[2] + red[3];
        float l = red[4] + red[5] + red[6] + red[7];
        double* slot = accum + (size_t)(orig & (NSLOT - 1)) * 2;
        atomicAdd(&slot[0], (double)l);
        atomicAdd(&slot[1], (double)s);
    }
}

__global__ __launch_bounds__(NSLOT) void photo_final(
    const double* __restrict__ accum, float* __restrict__ out, double invN)
{
    __shared__ double sl[8], ss[8];
    int tid = threadIdx.x;
    double l = accum[tid * 2 + 0];
    double s = accum[tid * 2 + 1];
    #pragma unroll
    for (int off = 32; off > 0; off >>= 1) {
        l += __shfl_down(l, off);
        s += __shfl_down(s, off);
    }
    if ((tid & 63) == 0) { sl[tid >> 6] = l; ss[tid >> 6] = s; }
    __syncthreads();
    if (tid == 0) {
        double L = 0.0, S = 0.0;
        #pragma unroll
        for (int i = 0; i < NSLOT / 64; ++i) { L += sl[i]; S += ss[i]; }
        double l1    = L * invN;
        double ssim  = S * invN;
        double dssim = (1.0 - ssim) * 0.5;
        out[0] = (float)(0.8 * l1 + 0.2 * dssim);
        out[1] = (float)l1;
        out[2] = (float)dssim;
    }
}

extern "C" void kernel_launch(void* const* d_in, const int* in_sizes, int n_in,
                              void* d_out, int out_size, void* d_ws, size_t ws_size,
                              hipStream_t stream)
{
    const int H = 1080, W = 1920, C = 3;
    const float* x = (const float*)d_in[0];
    const float* y = (const float*)d_in[1];
    int B = in_sizes[0] / (H * W * C);

    double* accum = (double*)d_ws;
    (void)hipMemsetAsync(d_ws, 0, NSLOT * 2 * sizeof(double), stream);

    dim3 grid(GX, GY, B);
    int nwg = GX * GY * B;
    photo_main<<<grid, dim3(256), 0, stream>>>(x, y, accum, B, nwg);

    double invN = 1.0 / ((double)B * H * W * C);
    photo_final<<<1, NSLOT, 0, stream>>>(accum, (float*)d_out, invN);
}

// Round 18
// 60.636 us; speedup vs baseline: 1.1102x; 1.1102x over previous
//
#include <hip/hip_runtime.h>
#include <hip/hip_fp16.h>

// PhotometricLoss: total = 0.8*L1 + 0.2*DSSIM; fused separable 11x11 Gaussian
// SSIM, SAME zero padding. Inputs BHWC fp32 (B=4,H=1080,W=1920,C=3).
// R18 (= R17 retried without the spill): launch_bounds(256,6) for VGPR
// headroom (~85) and UNCONDITIONAL clamped-address prefetch loads (no
// conditionally-initialized temps -> no scratch). Staging = 2-deep global
// load rotation; conv = next-channel LDS fragment prefetch. Else as R16.

typedef __fp16 hf4 __attribute__((ext_vector_type(4)));
typedef float f32x4 __attribute__((ext_vector_type(4)));

#define TW 32
#define TH 32
#define IH 42         // staged real rows
#define NPAIR 21      // data col-pairs per row
#define SPAIR 22      // row stride in uint2 (176 B; 12-bank rotation, ~2-way)
#define CHS (IH * SPAIR)   // uint2 per channel plane (924)
#define NITEMS (IH * NPAIR)
#define NSLOT 512
#define HH 1080
#define WW 1920
#define GX 60
#define GY 34

// Gaussian(sigma=1.5, 11 taps), normalized; matches fp32 reference within ~2e-7
static constexpr float G[11] = {
    0.00102838f, 0.00759876f, 0.03600077f, 0.10936069f, 0.21300554f,
    0.26601174f, 0.21300554f, 0.10936069f, 0.03600077f, 0.00759876f,
    0.00102838f};

// ---- constexpr f32 -> f16 bits (RNE); G values are all f16-normal
constexpr unsigned short f2h_cx(float f) {
    unsigned u = __builtin_bit_cast(unsigned, f);
    if ((u & 0x7fffffffu) == 0) return 0;
    int e = (int)((u >> 23) & 0xff) - 127 + 15;
    unsigned man = u & 0x7fffffu;
    unsigned m = man >> 13;
    unsigned rest = man & 0x1fffu;
    if (rest > 0x1000u || (rest == 0x1000u && (m & 1u))) {
        if (++m == 0x400u) { m = 0; ++e; }
    }
    return (unsigned short)((e << 10) | m);
}
constexpr float Gf(int d) { return (d >= 0 && d <= 10) ? G[d] : 0.0f; }
constexpr unsigned wpk(int d) {
    return (unsigned)f2h_cx(Gf(d)) | ((unsigned)f2h_cx(Gf(d + 1)) << 16);
}
// Band fragment tables (the only two nonzero tile-deltas):
// idx 0: halves g[lk - lr + i]; idx 1: g[16 + lk - lr + i].
struct WTbl {
    unsigned long long v[2][64];
    constexpr WTbl() : v{} {
        for (int dl = 0; dl < 2; ++dl)
            for (int l = 0; l < 64; ++l) {
                int d0 = 16 * dl + ((l >> 4) << 2) - (l & 15);
                v[dl][l] = (unsigned long long)wpk(d0) |
                           ((unsigned long long)wpk(d0 + 2) << 32);
            }
    }
};
__device__ const WTbl WT{};

struct f4u { float x, y, z, w; } __attribute__((packed, aligned(4)));

__device__ __forceinline__ unsigned int pkrtz(float a, float b) {
    return __builtin_bit_cast(unsigned int, __builtin_amdgcn_cvt_pkrtz(a, b));
}
__device__ __forceinline__ hf4 pk4(const f32x4& d) {
    uint2 u = make_uint2(pkrtz(d[0], d[1]), pkrtz(d[2], d[3]));
    return __builtin_bit_cast(hf4, u);
}
__device__ __forceinline__ f32x4 mfma16(hf4 a, hf4 b, f32x4 c) {
#if defined(__HIP_DEVICE_COMPILE__)
    return __builtin_amdgcn_mfma_f32_16x16x16f16(a, b, c, 0, 0, 0);
#else
    (void)a; (void)b;
    return c;   // host pass: never executed, just needs to parse
#endif
}

__global__ __launch_bounds__(256, 6) void photo_main(
    const float* __restrict__ xin, const float* __restrict__ yin,
    double* __restrict__ accum, int B, int nwg)
{
    __shared__ __align__(16) uint2 sXY[3 * CHS + 2];  // 22192 B, channel-outer
    __shared__ float red[8];

    // ---- bijective XCD swizzle (nwg % 8 == 0)
    int orig = blockIdx.x + GX * (blockIdx.y + GY * blockIdx.z);
    int nid = ((nwg & 7) == 0) ? ((orig & 7) * (nwg >> 3) + (orig >> 3)) : orig;
    int tx   = nid % GX;
    int rest = nid / GX;
    int by   = rest % GY;
    int b    = rest / GY;
    const int row0 = by * TH, col0 = tx * TW;
    const int tid  = threadIdx.x;
    const int lane = tid & 63;
    const int wid  = tid >> 6;
    const int imgbase = b * (HH * WW * 3);

    // ---- finite-fill: pair 21 of every (ch, row) + 2 slack words past ch2.
    // Read by the h-pass k2=2 tail with structurally-zero weights; must be
    // finite (not necessarily zero) to avoid NaN*0 in MFMA.
    if (tid < 126) {
        int ch = tid / IH, r = tid - ch * IH;
        sXY[ch * CHS + r * SPAIR + NPAIR] = make_uint2(0u, 0u);
    } else if (tid < 128) {
        sXY[3 * CHS + (tid - 126)] = make_uint2(0u, 0u);
    }

    // ---- Phase 1a: stage all 3 channels as interleaved (x,y) f16 pairs;
    // fold L1 over the central 32x32. Interior: 2-deep rotation with
    // UNCONDITIONAL clamped-address prefetch (no conditional init -> regs).
    float l1_sum = 0.f;
    const bool interior = (tx >= 1) && (tx <= 58) && (by >= 1) && (by <= 32);
    if (interior) {
        auto addr_of = [&](int i) {
            int ii = (i < NITEMS) ? i : (NITEMS - 1);   // clamp: always valid
            int r = ii / NPAIR, pc = ii - r * NPAIR;
            return imgbase + ((row0 - 5 + r) * WW + (col0 - 5 + 2 * pc)) * 3;
        };
        int base = addr_of(tid);
        f4u vx0 = *(const f4u*)&xin[base];
        f4u vx1 = *(const f4u*)&xin[base + 2];
        f4u vy0 = *(const f4u*)&yin[base];
        f4u vy1 = *(const f4u*)&yin[base + 2];
        #pragma unroll 1
        for (int i = tid; i < NITEMS; i += 256) {
            // issue NEXT item's loads before consuming current (clamped addr)
            int bn = addr_of(i + 256);
            f4u nx0 = *(const f4u*)&xin[bn];
            f4u nx1 = *(const f4u*)&xin[bn + 2];
            f4u ny0 = *(const f4u*)&yin[bn];
            f4u ny1 = *(const f4u*)&yin[bn + 2];
            int r = i / NPAIR, pc = i - r * NPAIR;
            float x0[3] = {vx0.x, vx0.y, vx0.z};
            float x1[3] = {vx1.y, vx1.z, vx1.w};
            float y0[3] = {vy0.x, vy0.y, vy0.z};
            float y1[3] = {vy1.y, vy1.z, vy1.w};
            #pragma unroll
            for (int c = 0; c < 3; ++c)
                sXY[c * CHS + r * SPAIR + pc] =
                    make_uint2(pkrtz(x0[c], x1[c]), pkrtz(y0[c], y1[c]));
            if (r >= 5 && r < 5 + TH) {
                if (pc >= 3 && pc <= 18)
                    l1_sum += fabsf(x0[0] - y0[0]) + fabsf(x0[1] - y0[1]) +
                              fabsf(x0[2] - y0[2]);
                if (pc >= 2 && pc <= 17)
                    l1_sum += fabsf(x1[0] - y1[0]) + fabsf(x1[1] - y1[1]) +
                              fabsf(x1[2] - y1[2]);
            }
            vx0 = nx0; vx1 = nx1; vy0 = ny0; vy1 = ny1;
        }
    } else {
        #pragma unroll 1
        for (int i = tid; i < NITEMS; i += 256) {
            int r  = i / NPAIR;
            int pc = i - r * NPAIR;
            int gr  = row0 - 5 + r;
            int gc0 = col0 - 5 + 2 * pc;
            bool rin = (unsigned)gr < (unsigned)HH;
            bool c0  = rin && ((unsigned)gc0       < (unsigned)WW);
            bool c1  = rin && ((unsigned)(gc0 + 1) < (unsigned)WW);
            int base = imgbase + (gr * WW + gc0) * 3;
            float x0[3] = {0.f, 0.f, 0.f}, x1[3] = {0.f, 0.f, 0.f};
            float y0[3] = {0.f, 0.f, 0.f}, y1[3] = {0.f, 0.f, 0.f};
            #pragma unroll
            for (int c = 0; c < 3; ++c) {
                if (c0) { x0[c] = xin[base + c];     y0[c] = yin[base + c]; }
                if (c1) { x1[c] = xin[base + 3 + c]; y1[c] = yin[base + 3 + c]; }
            }
            #pragma unroll
            for (int c = 0; c < 3; ++c)
                sXY[c * CHS + r * SPAIR + pc] =
                    make_uint2(pkrtz(x0[c], x1[c]), pkrtz(y0[c], y1[c]));
            if (r >= 5 && r < 5 + TH) {
                if (c0 && pc >= 3 && pc <= 18)
                    l1_sum += fabsf(x0[0] - y0[0]) + fabsf(x0[1] - y0[1]) +
                              fabsf(x0[2] - y0[2]);
                if (c1 && pc >= 2 && pc <= 17)
                    l1_sum += fabsf(x1[0] - y1[0]) + fabsf(x1[1] - y1[1]) +
                              fabsf(x1[2] - y1[2]);
            }
        }
    }
    __syncthreads();

    // ---- quadrant-per-wave conv: wave wid -> out quadrant (u,n), 16x16,
    // all 4 moment planes; register-chained h->v; SSIM from registers.
    // Channel loop: 2-deep LDS-read rotation, clamped channel index.
    const int lr = lane & 15;
    const int lk = (lane >> 4) << 2;
    const int u = wid >> 1, n = wid & 1;
    hf4 wfA = __builtin_bit_cast(hf4, WT.v[0][lane]);
    hf4 wfB = __builtin_bit_cast(hf4, WT.v[1][lane]);

    // clamped read rows: rows >= 42 (only t=2, lr >= 10) fold to row 41;
    // the garbage HC rows 42..47 carry structurally-zero v-pass weights.
    int rrow[2];
    #pragma unroll
    for (int dt = 0; dt < 2; ++dt)
        rrow[dt] = min(16 * (u + dt) + lr, IH - 1) * SPAIR;

    const float C1c = 1e-4f, C2c = 9e-4f;
    float ssim_sum = 0.f;
    const bool fullq = (row0 + 16 * u + 15) < HH;   // whole quadrant in-image
    uint4 rd[2][2];
    #pragma unroll
    for (int dt = 0; dt < 2; ++dt)
        #pragma unroll
        for (int dk = 0; dk < 2; ++dk)
            rd[dt][dk] = *(const uint4*)&sXY[rrow[dt] + 8 * (n + dk) + (lk >> 1)];
    #pragma unroll 1
    for (int ch = 0; ch < 3; ++ch) {
        // prefetch next channel's fragments (clamped: ch2 re-reads itself)
        const uint2* Sn = sXY + ((ch < 2) ? (ch + 1) : ch) * CHS;
        uint4 rn4[2][2];
        #pragma unroll
        for (int dt = 0; dt < 2; ++dt)
            #pragma unroll
            for (int dk = 0; dk < 2; ++dk)
                rn4[dt][dk] = *(const uint4*)
                    &Sn[rrow[dt] + 8 * (n + dk) + (lk >> 1)];
        // h-pass: HC tiles t=u,u+1 for col-block n, 4 planes
        hf4 bfr[4][2];
        #pragma unroll
        for (int dt = 0; dt < 2; ++dt) {
            f32x4 d[4];
            #pragma unroll
            for (int p = 0; p < 4; ++p) d[p] = (f32x4){0.f, 0.f, 0.f, 0.f};
            #pragma unroll
            for (int dk = 0; dk < 2; ++dk) {
                uint4 v = rd[dt][dk];
                hf4 xv = __builtin_bit_cast(hf4, make_uint2(v.x, v.z));
                hf4 yv = __builtin_bit_cast(hf4, make_uint2(v.y, v.w));
                hf4 zv = xv * xv + yv * yv;
                hf4 wv = xv * yv;
                hf4 wB = dk ? wfB : wfA;
                d[0] = mfma16(xv, wB, d[0]);
                d[1] = mfma16(yv, wB, d[1]);
                d[2] = mfma16(zv, wB, d[2]);
                d[3] = mfma16(wv, wB, d[3]);
            }
            #pragma unroll
            for (int p = 0; p < 4; ++p) bfr[p][dt] = pk4(d[p]);
        }
        // v-pass: OUT quadrant = Wv x HC
        f32x4 vacc[4];
        #pragma unroll
        for (int p = 0; p < 4; ++p) {
            vacc[p] = (f32x4){0.f, 0.f, 0.f, 0.f};
            vacc[p] = mfma16(wfA, bfr[p][0], vacc[p]);
            vacc[p] = mfma16(wfB, bfr[p][1], vacc[p]);
        }
        // SSIM directly from registers
        if (fullq) {
            #pragma unroll
            for (int g2 = 0; g2 < 4; ++g2) {
                float mu1 = vacc[0][g2], mu2 = vacc[1][g2];
                float s2s = vacc[2][g2], s12 = vacc[3][g2];
                float mu1s = mu1 * mu1, mu2s = mu2 * mu2, mu12 = mu1 * mu2;
                float ssum = s2s - mu1s - mu2s;
                float sxy  = s12 - mu12;
                float num = (2.f * mu12 + C1c) * (2.f * sxy + C2c);
                float den = (mu1s + mu2s + C1c) * (ssum + C2c);
                ssim_sum += num * __builtin_amdgcn_rcpf(den);
            }
        } else {
            #pragma unroll
            for (int g2 = 0; g2 < 4; ++g2) {
                int gr = row0 + 16 * u + lk + g2;
                if (gr < HH) {
                    float mu1 = vacc[0][g2], mu2 = vacc[1][g2];
                    float s2s = vacc[2][g2], s12 = vacc[3][g2];
                    float mu1s = mu1 * mu1, mu2s = mu2 * mu2, mu12 = mu1 * mu2;
                    float ssum = s2s - mu1s - mu2s;
                    float sxy  = s12 - mu12;
                    float num = (2.f * mu12 + C1c) * (2.f * sxy + C2c);
                    float den = (mu1s + mu2s + C1c) * (ssum + C2c);
                    ssim_sum += num * __builtin_amdgcn_rcpf(den);
                }
            }
        }
        #pragma unroll
        for (int dt = 0; dt < 2; ++dt)
            #pragma unroll
            for (int dk = 0; dk < 2; ++dk)
                rd[dt][dk] = rn4[dt][dk];
    }

    // ---- Block reduction, then hashed double atomics
    #pragma unroll
    for (int off = 32; off > 0; off >>= 1) {
        ssim_sum += __shfl_down(ssim_sum, off);
        l1_sum   += __shfl_down(l1_sum, off);
    }
    if ((tid & 63) == 0) { red[wid] = ssim_sum; red[4 + wid] = l1_sum; }
    __syncthreads();
    if (tid == 0) {
        float s = red[0] + red[1] + red[2] + red[3];
        float l = red[4] + red[5] + red[6] + red[7];
        double* slot = accum + (size_t)(orig & (NSLOT - 1)) * 2;
        atomicAdd(&slot[0], (double)l);
        atomicAdd(&slot[1], (double)s);
    }
}

__global__ __launch_bounds__(NSLOT) void photo_final(
    const double* __restrict__ accum, float* __restrict__ out, double invN)
{
    __shared__ double sl[8], ss[8];
    int tid = threadIdx.x;
    double l = accum[tid * 2 + 0];
    double s = accum[tid * 2 + 1];
    #pragma unroll
    for (int off = 32; off > 0; off >>= 1) {
        l += __shfl_down(l, off);
        s += __shfl_down(s, off);
    }
    if ((tid & 63) == 0) { sl[tid >> 6] = l; ss[tid >> 6] = s; }
    __syncthreads();
    if (tid == 0) {
        double L = 0.0, S = 0.0;
        #pragma unroll
        for (int i = 0; i < NSLOT / 64; ++i) { L += sl[i]; S += ss[i]; }
        double l1    = L * invN;
        double ssim  = S * invN;
        double dssim = (1.0 - ssim) * 0.5;
        out[0] = (float)(0.8 * l1 + 0.2 * dssim);
        out[1] = (float)l1;
        out[2] = (float)dssim;
    }
}

extern "C" void kernel_launch(void* const* d_in, const int* in_sizes, int n_in,
                              void* d_out, int out_size, void* d_ws, size_t ws_size,
                              hipStream_t stream)
{
    const int H = 1080, W = 1920, C = 3;
    const float* x = (const float*)d_in[0];
    const float* y = (const float*)d_in[1];
    int B = in_sizes[0] / (H * W * C);

    double* accum = (double*)d_ws;
    (void)hipMemsetAsync(d_ws, 0, NSLOT * 2 * sizeof(double), stream);

    dim3 grid(GX, GY, B);
    int nwg = GX * GY * B;
    photo_main<<<grid, dim3(256), 0, stream>>>(x, y, accum, B, nwg);

    double invN = 1.0 / ((double)B * H * W * C);
    photo_final<<<1, NSLOT, 0, stream>>>(accum, (float*)d_out, invN);
}

// Round 19
// 58.221 us; speedup vs baseline: 1.1562x; 1.0415x over previous
//
#include <hip/hip_runtime.h>
#include <hip/hip_fp16.h>

// PhotometricLoss: total = 0.8*L1 + 0.2*DSSIM; fused separable 11x11 Gaussian
// SSIM, SAME zero padding. Inputs BHWC fp32 (B=4,H=1080,W=1920,C=3).
// R19 = R16 verbatim (best: 58.1 us). MFMA banded-GEMM conv, all-3-channels
// per block, quadrant-per-wave, register-chained h->v, SSIM from registers.
// SPAIR 22: h-pass k2=2 tail columns are STRUCTURALLY zero-weighted
// (g-index >= 11 for k_local >= 10), so out-of-row halves need only be
// FINITE; pairs 22,23 alias the next row's data; only pair 21/row + 2 slack
// words are zeroed (NaN*0 = NaN in MFMA). LDS 21.7 KB -> 7 blocks/CU.
// Session ladder: 643 -> 204 -> 169 -> 129 -> 114 -> 107 (VALU dot2 era)
// -> 90.6 (MFMA) -> 60.5 (3ch/block kills L2 amplification) -> 58.1 (this).
// Issue-bound: rocprof busy (VALU 40us + MFMA 15us) ~= 95% of bench dur.

typedef __fp16 hf4 __attribute__((ext_vector_type(4)));
typedef float f32x4 __attribute__((ext_vector_type(4)));

#define TW 32
#define TH 32
#define IH 42         // staged real rows
#define NPAIR 21      // data col-pairs per row
#define SPAIR 22      // row stride in uint2 (176 B; 12-bank rotation, ~2-way)
#define CHS (IH * SPAIR)   // uint2 per channel plane (924)
#define NSLOT 512
#define HH 1080
#define WW 1920
#define GX 60
#define GY 34

// Gaussian(sigma=1.5, 11 taps), normalized; matches fp32 reference within ~2e-7
static constexpr float G[11] = {
    0.00102838f, 0.00759876f, 0.03600077f, 0.10936069f, 0.21300554f,
    0.26601174f, 0.21300554f, 0.10936069f, 0.03600077f, 0.00759876f,
    0.00102838f};

// ---- constexpr f32 -> f16 bits (RNE); G values are all f16-normal
constexpr unsigned short f2h_cx(float f) {
    unsigned u = __builtin_bit_cast(unsigned, f);
    if ((u & 0x7fffffffu) == 0) return 0;
    int e = (int)((u >> 23) & 0xff) - 127 + 15;
    unsigned man = u & 0x7fffffu;
    unsigned m = man >> 13;
    unsigned rest = man & 0x1fffu;
    if (rest > 0x1000u || (rest == 0x1000u && (m & 1u))) {
        if (++m == 0x400u) { m = 0; ++e; }
    }
    return (unsigned short)((e << 10) | m);
}
constexpr float Gf(int d) { return (d >= 0 && d <= 10) ? G[d] : 0.0f; }
constexpr unsigned wpk(int d) {
    return (unsigned)f2h_cx(Gf(d)) | ((unsigned)f2h_cx(Gf(d + 1)) << 16);
}
// Band fragment tables (the only two nonzero tile-deltas):
// idx 0: halves g[lk - lr + i]; idx 1: g[16 + lk - lr + i].
struct WTbl {
    unsigned long long v[2][64];
    constexpr WTbl() : v{} {
        for (int dl = 0; dl < 2; ++dl)
            for (int l = 0; l < 64; ++l) {
                int d0 = 16 * dl + ((l >> 4) << 2) - (l & 15);
                v[dl][l] = (unsigned long long)wpk(d0) |
                           ((unsigned long long)wpk(d0 + 2) << 32);
            }
    }
};
__device__ const WTbl WT{};

struct f4u { float x, y, z, w; } __attribute__((packed, aligned(4)));

__device__ __forceinline__ unsigned int pkrtz(float a, float b) {
    return __builtin_bit_cast(unsigned int, __builtin_amdgcn_cvt_pkrtz(a, b));
}
__device__ __forceinline__ hf4 pk4(const f32x4& d) {
    uint2 u = make_uint2(pkrtz(d[0], d[1]), pkrtz(d[2], d[3]));
    return __builtin_bit_cast(hf4, u);
}
__device__ __forceinline__ f32x4 mfma16(hf4 a, hf4 b, f32x4 c) {
#if defined(__HIP_DEVICE_COMPILE__)
    return __builtin_amdgcn_mfma_f32_16x16x16f16(a, b, c, 0, 0, 0);
#else
    (void)a; (void)b;
    return c;   // host pass: never executed, just needs to parse
#endif
}

__global__ __launch_bounds__(256, 7) void photo_main(
    const float* __restrict__ xin, const float* __restrict__ yin,
    double* __restrict__ accum, int B, int nwg)
{
    __shared__ __align__(16) uint2 sXY[3 * CHS + 2];  // 22192 B, channel-outer
    __shared__ float red[8];

    // ---- bijective XCD swizzle (nwg % 8 == 0)
    int orig = blockIdx.x + GX * (blockIdx.y + GY * blockIdx.z);
    int nid = ((nwg & 7) == 0) ? ((orig & 7) * (nwg >> 3) + (orig >> 3)) : orig;
    int tx   = nid % GX;
    int rest = nid / GX;
    int by   = rest % GY;
    int b    = rest / GY;
    const int row0 = by * TH, col0 = tx * TW;
    const int tid  = threadIdx.x;
    const int lane = tid & 63;
    const int wid  = tid >> 6;
    const int imgbase = b * (HH * WW * 3);

    // ---- finite-fill: pair 21 of every (ch, row) + 2 slack words past ch2.
    // Read by the h-pass k2=2 tail with structurally-zero weights; must be
    // finite (not necessarily zero) to avoid NaN*0 in MFMA.
    if (tid < 126) {
        int ch = tid / IH, r = tid - ch * IH;
        sXY[ch * CHS + r * SPAIR + NPAIR] = make_uint2(0u, 0u);
    } else if (tid < 128) {
        sXY[3 * CHS + (tid - 126)] = make_uint2(0u, 0u);
    }

    // ---- Phase 1a: stage all 3 channels as interleaved (x,y) f16 pairs;
    // fold L1 (all channels) over the central 32x32.
    float l1_sum = 0.f;
    const bool interior = (tx >= 1) && (tx <= 58) && (by >= 1) && (by <= 32);
    if (interior) {
        for (int i = tid; i < IH * NPAIR; i += 256) {
            int r  = i / NPAIR;
            int pc = i - r * NPAIR;
            int gr  = row0 - 5 + r;
            int gc0 = col0 - 5 + 2 * pc;
            int base = imgbase + (gr * WW + gc0) * 3;
            f4u vx0 = *(const f4u*)&xin[base];        // x0c0 x0c1 x0c2 x1c0
            f4u vx1 = *(const f4u*)&xin[base + 2];    // x0c2 x1c0 x1c1 x1c2
            f4u vy0 = *(const f4u*)&yin[base];
            f4u vy1 = *(const f4u*)&yin[base + 2];
            float x0[3] = {vx0.x, vx0.y, vx0.z};
            float x1[3] = {vx1.y, vx1.z, vx1.w};
            float y0[3] = {vy0.x, vy0.y, vy0.z};
            float y1[3] = {vy1.y, vy1.z, vy1.w};
            #pragma unroll
            for (int c = 0; c < 3; ++c)
                sXY[c * CHS + r * SPAIR + pc] =
                    make_uint2(pkrtz(x0[c], x1[c]), pkrtz(y0[c], y1[c]));
            if (r >= 5 && r < 5 + TH) {
                if (pc >= 3 && pc <= 18)
                    l1_sum += fabsf(x0[0] - y0[0]) + fabsf(x0[1] - y0[1]) +
                              fabsf(x0[2] - y0[2]);
                if (pc >= 2 && pc <= 17)
                    l1_sum += fabsf(x1[0] - y1[0]) + fabsf(x1[1] - y1[1]) +
                              fabsf(x1[2] - y1[2]);
            }
        }
    } else {
        #pragma unroll 1
        for (int i = tid; i < IH * NPAIR; i += 256) {
            int r  = i / NPAIR;
            int pc = i - r * NPAIR;
            int gr  = row0 - 5 + r;
            int gc0 = col0 - 5 + 2 * pc;
            bool rin = (unsigned)gr < (unsigned)HH;
            bool c0  = rin && ((unsigned)gc0       < (unsigned)WW);
            bool c1  = rin && ((unsigned)(gc0 + 1) < (unsigned)WW);
            int base = imgbase + (gr * WW + gc0) * 3;
            float x0[3] = {0.f, 0.f, 0.f}, x1[3] = {0.f, 0.f, 0.f};
            float y0[3] = {0.f, 0.f, 0.f}, y1[3] = {0.f, 0.f, 0.f};
            #pragma unroll
            for (int c = 0; c < 3; ++c) {
                if (c0) { x0[c] = xin[base + c];     y0[c] = yin[base + c]; }
                if (c1) { x1[c] = xin[base + 3 + c]; y1[c] = yin[base + 3 + c]; }
            }
            #pragma unroll
            for (int c = 0; c < 3; ++c)
                sXY[c * CHS + r * SPAIR + pc] =
                    make_uint2(pkrtz(x0[c], x1[c]), pkrtz(y0[c], y1[c]));
            if (r >= 5 && r < 5 + TH) {
                if (c0 && pc >= 3 && pc <= 18)
                    l1_sum += fabsf(x0[0] - y0[0]) + fabsf(x0[1] - y0[1]) +
                              fabsf(x0[2] - y0[2]);
                if (c1 && pc >= 2 && pc <= 17)
                    l1_sum += fabsf(x1[0] - y1[0]) + fabsf(x1[1] - y1[1]) +
                              fabsf(x1[2] - y1[2]);
            }
        }
    }
    __syncthreads();

    // ---- quadrant-per-wave conv: wave wid -> out quadrant (u,n), 16x16,
    // all 4 moment planes; register-chained h->v; SSIM from registers.
    const int lr = lane & 15;
    const int lk = (lane >> 4) << 2;
    const int u = wid >> 1, n = wid & 1;
    hf4 wfA = __builtin_bit_cast(hf4, WT.v[0][lane]);
    hf4 wfB = __builtin_bit_cast(hf4, WT.v[1][lane]);

    // clamped read rows: rows >= 42 (only t=2, lr >= 10) fold to row 41;
    // the garbage HC rows 42..47 carry structurally-zero v-pass weights.
    int rrow[2];
    #pragma unroll
    for (int dt = 0; dt < 2; ++dt)
        rrow[dt] = min(16 * (u + dt) + lr, IH - 1) * SPAIR;

    const float C1c = 1e-4f, C2c = 9e-4f;
    float ssim_sum = 0.f;
    const bool fullq = (row0 + 16 * u + 15) < HH;   // whole quadrant in-image
    #pragma unroll 1
    for (int ch = 0; ch < 3; ++ch) {
        const uint2* S = sXY + ch * CHS;
        // read the 4 staged b128 fragments (t = u+dt, k2 = n+dk)
        uint4 rd[2][2];
        #pragma unroll
        for (int dt = 0; dt < 2; ++dt)
            #pragma unroll
            for (int dk = 0; dk < 2; ++dk)
                rd[dt][dk] = *(const uint4*)
                    &S[rrow[dt] + 8 * (n + dk) + (lk >> 1)];
        // h-pass: HC tiles t=u,u+1 for col-block n, 4 planes
        hf4 bfr[4][2];
        #pragma unroll
        for (int dt = 0; dt < 2; ++dt) {
            f32x4 d[4];
            #pragma unroll
            for (int p = 0; p < 4; ++p) d[p] = (f32x4){0.f, 0.f, 0.f, 0.f};
            #pragma unroll
            for (int dk = 0; dk < 2; ++dk) {
                uint4 v = rd[dt][dk];
                hf4 xv = __builtin_bit_cast(hf4, make_uint2(v.x, v.z));
                hf4 yv = __builtin_bit_cast(hf4, make_uint2(v.y, v.w));
                hf4 zv = xv * xv + yv * yv;
                hf4 wv = xv * yv;
                hf4 wB = dk ? wfB : wfA;
                d[0] = mfma16(xv, wB, d[0]);
                d[1] = mfma16(yv, wB, d[1]);
                d[2] = mfma16(zv, wB, d[2]);
                d[3] = mfma16(wv, wB, d[3]);
            }
            #pragma unroll
            for (int p = 0; p < 4; ++p) bfr[p][dt] = pk4(d[p]);
        }
        // v-pass: OUT quadrant = Wv x HC
        f32x4 vacc[4];
        #pragma unroll
        for (int p = 0; p < 4; ++p) {
            vacc[p] = (f32x4){0.f, 0.f, 0.f, 0.f};
            vacc[p] = mfma16(wfA, bfr[p][0], vacc[p]);
            vacc[p] = mfma16(wfB, bfr[p][1], vacc[p]);
        }
        // SSIM directly from registers
        if (fullq) {
            #pragma unroll
            for (int g2 = 0; g2 < 4; ++g2) {
                float mu1 = vacc[0][g2], mu2 = vacc[1][g2];
                float s2s = vacc[2][g2], s12 = vacc[3][g2];
                float mu1s = mu1 * mu1, mu2s = mu2 * mu2, mu12 = mu1 * mu2;
                float ssum = s2s - mu1s - mu2s;
                float sxy  = s12 - mu12;
                float num = (2.f * mu12 + C1c) * (2.f * sxy + C2c);
                float den = (mu1s + mu2s + C1c) * (ssum + C2c);
                ssim_sum += num * __builtin_amdgcn_rcpf(den);
            }
        } else {
            #pragma unroll
            for (int g2 = 0; g2 < 4; ++g2) {
                int gr = row0 + 16 * u + lk + g2;
                if (gr < HH) {
                    float mu1 = vacc[0][g2], mu2 = vacc[1][g2];
                    float s2s = vacc[2][g2], s12 = vacc[3][g2];
                    float mu1s = mu1 * mu1, mu2s = mu2 * mu2, mu12 = mu1 * mu2;
                    float ssum = s2s - mu1s - mu2s;
                    float sxy  = s12 - mu12;
                    float num = (2.f * mu12 + C1c) * (2.f * sxy + C2c);
                    float den = (mu1s + mu2s + C1c) * (ssum + C2c);
                    ssim_sum += num * __builtin_amdgcn_rcpf(den);
                }
            }
        }
    }

    // ---- Block reduction, then hashed double atomics
    #pragma unroll
    for (int off = 32; off > 0; off >>= 1) {
        ssim_sum += __shfl_down(ssim_sum, off);
        l1_sum   += __shfl_down(l1_sum, off);
    }
    if ((tid & 63) == 0) { red[wid] = ssim_sum; red[4 + wid] = l1_sum; }
    __syncthreads();
    if (tid == 0) {
        float s = red[0] + red[1] + red[2] + red[3];
        float l = red[4] + red[5] + red[6] + red[7];
        double* slot = accum + (size_t)(orig & (NSLOT - 1)) * 2;
        atomicAdd(&slot[0], (double)l);
        atomicAdd(&slot[1], (double)s);
    }
}

__global__ __launch_bounds__(NSLOT) void photo_final(
    const double* __restrict__ accum, float* __restrict__ out, double invN)
{
    __shared__ double sl[8], ss[8];
    int tid = threadIdx.x;
    double l = accum[tid * 2 + 0];
    double s = accum[tid * 2 + 1];
    #pragma unroll
    for (int off = 32; off > 0; off >>= 1) {
        l += __shfl_down(l, off);
        s += __shfl_down(s, off);
    }
    if ((tid & 63) == 0) { sl[tid >> 6] = l; ss[tid >> 6] = s; }
    __syncthreads();
    if (tid == 0) {
        double L = 0.0, S = 0.0;
        #pragma unroll
        for (int i = 0; i < NSLOT / 64; ++i) { L += sl[i]; S += ss[i]; }
        double l1    = L * invN;
        double ssim  = S * invN;
        double dssim = (1.0 - ssim) * 0.5;
        out[0] = (float)(0.8 * l1 + 0.2 * dssim);
        out[1] = (float)l1;
        out[2] = (float)dssim;
    }
}

extern "C" void kernel_launch(void* const* d_in, const int* in_sizes, int n_in,
                              void* d_out, int out_size, void* d_ws, size_t ws_size,
                              hipStream_t stream)
{
    const int H = 1080, W = 1920, C = 3;
    const float* x = (const float*)d_in[0];
    const float* y = (const float*)d_in[1];
    int B = in_sizes[0] / (H * W * C);

    double* accum = (double*)d_ws;
    (void)hipMemsetAsync(d_ws, 0, NSLOT * 2 * sizeof(double), stream);

    dim3 grid(GX, GY, B);
    int nwg = GX * GY * B;
    photo_main<<<grid, dim3(256), 0, stream>>>(x, y, accum, B, nwg);

    double invN = 1.0 / ((double)B * H * W * C);
    photo_final<<<1, NSLOT, 0, stream>>>(accum, (float*)d_out, invN);
}